// Round 4
// baseline (206.273 us; speedup 1.0000x reference)
//
#include <hip/hip_runtime.h>
#include <math.h>

// Problem constants (from reference): S=7, NB=2, C=20
#define SS 7
#define CC 20
#define CELL_PRED 30            // C + NB*5  (120 B/cell)
#define CELL_TGT  25            // C + 1 + 4 (100 B/cell)
#define TPB 256                 // 4 waves/block, wave-PRIVATE staging: no hot-loop barriers
#define WAVES 4
#define GRID 512                // 2 blocks/CU resident -> 8 waves/CU; partials fit 4KB ws
#define NW (GRID * WAVES)       // 2048 concurrent wave-streams
#define REDUCE_BLOCK 256

// R9 theory: R0-R3 = four structures, one wall (66-70us, 4.3 B/cy/CU read).
// Common factor: bursty in-flight profile -- each wave drains its 14KB then
// computes ~900cy holding ZERO bytes in flight; average outstanding/CU is far
// below the Little's-law requirement at loaded latency. Fix = T14 async-STAGE
// split: per iteration {issue tile t+1 loads -> registers | compute tile t
// from LDS (loads in flight the whole time) | ds_write tile t+1}. ds_writes
// cannot hoist above compute's ds_reads (same-buffer aliasing); a
// sched_barrier(0) pins load-issue above compute. Every wave then holds 14KB
// in flight continuously -> ~112KB/CU sustained vs the ~25-100KB needed to
// saturate the fabric at 2-3k cy loaded latency.
//
// Tile geometry (per wave): 64 cells.
//   pred slab: 64*120 = 7680 B -> 7x float4 + 1x float2 per lane (coalesced)
//   tgt  slab: 64*100 = 6400 B -> 6x float4 + 1x dword  per lane (coalesced)

#define PRED_TILE_B 7680
#define TGT_TILE_B  6400
#define TILE_FLOATS 3520        // (7680+6400)/4 floats per wave-buffer

struct TileRegs {               // 55 VGPRs of in-flight tile data per lane
    float4 rp[7];
    float2 rpt;
    float4 rt[6];
    float  rtt;
};

__device__ __forceinline__ void load_tile(const float* __restrict__ pred,
                                          const float* __restrict__ tgt,
                                          size_t t, int lane, TileRegs& r)
{
    const float4* gp4 = (const float4*)((const char*)pred + t * (size_t)PRED_TILE_B);
    const float2* gp2 = (const float2*)gp4;
    const float4* gt4 = (const float4*)((const char*)tgt  + t * (size_t)TGT_TILE_B);
    const float*  gt1 = (const float*)gt4;
    #pragma unroll
    for (int k = 0; k < 7; ++k) r.rp[k] = gp4[k * 64 + lane];    // 7x1024B
    r.rpt = gp2[896 + lane];                                      // 512B @7168
    #pragma unroll
    for (int k = 0; k < 6; ++k) r.rt[k] = gt4[k * 64 + lane];    // 6x1024B
    r.rtt = gt1[1536 + lane];                                     // 256B @6144
}

__device__ __forceinline__ void write_tile(float* lbuf, int lane, const TileRegs& r)
{
    float4* lp4 = (float4*)lbuf;
    #pragma unroll
    for (int k = 0; k < 7; ++k) lp4[k * 64 + lane] = r.rp[k];
    ((float2*)lbuf)[896 + lane] = r.rpt;
    float4* lt4 = (float4*)(lbuf + PRED_TILE_B / 4);
    #pragma unroll
    for (int k = 0; k < 6; ++k) lt4[k * 64 + lane] = r.rt[k];
    (lbuf + PRED_TILE_B / 4)[1536 + lane] = r.rtt;
}

// pc = this cell's 30 pred floats (8B-aligned), tc = its 25 tgt floats.
// Works for both LDS (hot path) and global (ragged tail) pointers.
__device__ __forceinline__ float cell_loss_ptr(const float* __restrict__ pc,
                                               const float* __restrict__ tc) {
    const float EPS = 1e-6f;
    float tv[CELL_TGT];
    #pragma unroll
    for (int j = 0; j < CELL_TGT; ++j) tv[j] = tc[j];

    const float2* p2 = (const float2*)pc;
    float cls = 0.0f;
    #pragma unroll
    for (int j = 0; j < 10; ++j) {
        float2 v = p2[j];
        float d0 = v.x - tv[2 * j];
        float d1 = v.y - tv[2 * j + 1];
        cls += d0 * d0;
        cls += d1 * d1;
    }
    float b[10];
    #pragma unroll
    for (int j = 0; j < 5; ++j) {
        float2 v = p2[10 + j];
        b[2 * j] = v.x; b[2 * j + 1] = v.y;
    }
    const float* b1 = b;        // pred[20..24]
    const float* b2 = b + 5;    // pred[25..29]
    const float* tb = tv + CC;  // tgt[20..24]

    float obj = (tb[0] == 1.0f) ? 1.0f : 0.0f;

    float t_x1 = tb[0] - tb[2] * 0.5f, t_y1 = tb[1] - tb[3] * 0.5f;
    float t_x2 = tb[0] + tb[2] * 0.5f, t_y2 = tb[1] + tb[3] * 0.5f;
    float t_area = fabsf((t_x2 - t_x1) * (t_y2 - t_y1));

    float a_x1 = b1[0] - b1[2] * 0.5f, a_y1 = b1[1] - b1[3] * 0.5f;
    float a_x2 = b1[0] + b1[2] * 0.5f, a_y2 = b1[1] + b1[3] * 0.5f;
    float iw1 = fmaxf(fminf(a_x2, t_x2) - fmaxf(a_x1, t_x1), 0.0f);
    float ih1 = fmaxf(fminf(a_y2, t_y2) - fmaxf(a_y1, t_y1), 0.0f);
    float inter1 = iw1 * ih1;
    float area1 = fabsf((a_x2 - a_x1) * (a_y2 - a_y1));
    float iou1 = inter1 / (area1 + t_area - inter1 + EPS);

    float c_x1 = b2[0] - b2[2] * 0.5f, c_y1 = b2[1] - b2[3] * 0.5f;
    float c_x2 = b2[0] + b2[2] * 0.5f, c_y2 = b2[1] + b2[3] * 0.5f;
    float iw2 = fmaxf(fminf(c_x2, t_x2) - fmaxf(c_x1, t_x1), 0.0f);
    float ih2 = fmaxf(fminf(c_y2, t_y2) - fmaxf(c_y1, t_y1), 0.0f);
    float inter2 = iw2 * ih2;
    float area2 = fabsf((c_x2 - c_x1) * (c_y2 - c_y1));
    float iou2 = inter2 / (area2 + t_area - inter2 + EPS);

    bool pick1 = iou1 > iou2;
    float r0 = pick1 ? b1[0] : b2[0];
    float r1 = pick1 ? b1[1] : b2[1];
    float r2 = pick1 ? b1[2] : b2[2];
    float r3 = pick1 ? b1[3] : b2[3];
    float r4 = pick1 ? b1[4] : b2[4];

    float dx = r0 - tb[0], dy = r1 - tb[1];
    float xy = dx * dx + dy * dy;
    float dw = sqrtf(r2) - sqrtf(tb[2]);
    float dh = sqrtf(r3) - sqrtf(tb[3]);
    float wh = dw * dw + dh * dh;
    float coord = 5.0f * (xy + wh);
    float dconf = r4 - tb[4];
    float conf = dconf * dconf;

    float noobj = 0.5f * (1.0f - obj) * (b1[4] * b1[4] + b2[4] * b2[4]);
    return obj * (coord + conf + cls) + noobj;
}

__global__ __launch_bounds__(TPB, 2) void yolo_stream(
    const float* __restrict__ pred,
    const float* __restrict__ tgt,
    float* __restrict__ partials,     // [GRID]
    int nCells)
{
    __shared__ __align__(16) float lds[WAVES][TILE_FLOATS];  // 56,320 B
    __shared__ float s_red[WAVES];
    const int tid  = threadIdx.x;
    const int lane = tid & 63;
    const int wid  = tid >> 6;
    const int gw   = blockIdx.x * WAVES + wid;   // global wave-stream id, 0..NW-1
    const int nTiles = nCells >> 6;              // 12544

    float* buf = lds[wid];                       // wave-private buffer
    float loss = 0.0f;

    // tiles gw, gw+NW, gw+2NW, ...
    const int myT = (gw < nTiles) ? ((nTiles - gw - 1) / NW + 1) : 0;

    if (myT > 0) {
        TileRegs r;
        size_t t = (size_t)gw;
        load_tile(pred, tgt, t, lane, r);        // tile 0 -> regs
        write_tile(buf, lane, r);                // counted vmcnt drain -> LDS
        for (int i = 0; i < myT; ++i) {
            t += NW;
            if (i + 1 < myT)
                load_tile(pred, tgt, t, lane, r);    // PREFETCH: issue early
            __builtin_amdgcn_sched_barrier(0);       // pin issue above compute
            loss += cell_loss_ptr(buf + lane * CELL_PRED,
                                  buf + (PRED_TILE_B / 4) + lane * CELL_TGT);
            if (i + 1 < myT)
                write_tile(buf, lane, r);            // WRITE LATE: after compute
        }
    }

    // ragged tail (nCells % 64 != 0; zero for N=16384): direct global path
    if (gw == 0) {
        for (int c = (nTiles << 6) + lane; c < nCells; c += 64)
            loss += cell_loss_ptr(pred + (size_t)c * CELL_PRED,
                                  tgt  + (size_t)c * CELL_TGT);
    }

    // per-wave butterfly, then 4 waves via tiny LDS (single barrier, post-loop)
    #pragma unroll
    for (int off = 32; off > 0; off >>= 1)
        loss += __shfl_down(loss, off, 64);
    if (lane == 0) s_red[wid] = loss;
    __syncthreads();
    if (tid == 0)
        partials[blockIdx.x] = (s_red[0] + s_red[1]) + (s_red[2] + s_red[3]);
}

__global__ __launch_bounds__(REDUCE_BLOCK) void yolo_final_reduce(
    const float* __restrict__ partials, int nPartials, double invN,
    float* __restrict__ out)
{
    __shared__ double s_red[4];
    const float4* p4 = (const float4*)partials;   // d_ws is 16-aligned
    double sum = 0.0;
    for (int i = threadIdx.x; i < (nPartials >> 2); i += REDUCE_BLOCK) {
        float4 v = p4[i];
        sum += (double)v.x + (double)v.y + (double)v.z + (double)v.w;
    }
    for (int i = ((nPartials >> 2) << 2) + threadIdx.x; i < nPartials; i += REDUCE_BLOCK)
        sum += (double)partials[i];
    #pragma unroll
    for (int off = 32; off > 0; off >>= 1)
        sum += __shfl_down(sum, off, 64);
    if ((threadIdx.x & 63) == 0) s_red[threadIdx.x >> 6] = sum;
    __syncthreads();
    if (threadIdx.x == 0) {
        double s = (s_red[0] + s_red[1]) + (s_red[2] + s_red[3]);
        out[0] = (float)(s * invN);
    }
}

extern "C" void kernel_launch(void* const* d_in, const int* in_sizes, int n_in,
                              void* d_out, int out_size, void* d_ws, size_t ws_size,
                              hipStream_t stream) {
    const float* pred = (const float*)d_in[0];
    const float* tgt  = (const float*)d_in[1];
    float* out = (float*)d_out;
    float* partials = (float*)d_ws;

    const int N = in_sizes[0] / (SS * SS * CELL_PRED);   // 16384
    const int nCells = N * SS * SS;                      // 802816

    yolo_stream<<<GRID, TPB, 0, stream>>>(pred, tgt, partials, nCells);
    yolo_final_reduce<<<1, REDUCE_BLOCK, 0, stream>>>(partials, GRID, 1.0 / (double)N, out);
}

// Round 5
// 205.316 us; speedup vs baseline: 1.0047x; 1.0047x over previous
//
#include <hip/hip_runtime.h>
#include <math.h>

// Problem constants (from reference): S=7, NB=2, C=20
#define SS 7
#define CC 20
#define CELL_PRED 30            // C + NB*5  (120 B/cell)
#define CELL_TGT  25            // C + 1 + 4 (100 B/cell)
#define TPB 256                 // 4 waves/block
#define WAVES 4
#define GRID 1024               // partials = 1024 floats = 4 KB (known-good ws size)
#define NSTREAM (GRID * WAVES)  // 4096 wave-streams
#define REDUCE_BLOCK 256

// R10 theory: R4's accidental spill PROVED the memory system delivers
// >=3.3 TB/s reads / 8.6 B/cy/CU total to these CUs -- the 4.3 B/cy/CU
// plateau of R1-R3 is structural to the global->LDS->ds_read consumption
// path, and R0's identical 70us was a different wall (40 strided instrs
// x 64 lines of TA scatter). R5 removes BOTH: no LDS anywhere, and full
// float4 alignment by giving each lane 4 CONSECUTIVE cells:
//   pred window: 4*120 B = 480 B = exactly 30 float4s, 16B-aligned
//   tgt  window: 4*100 B = 400 B = exactly 25 float4s, 16B-aligned
// ~15 aligned float4 loads per cell slice, all statically indexed (no
// scratch), consumed cell-by-cell so peak live regs stay ~60-90. This is
// structurally the m13 copy bench (6.29 TB/s) plus VALU.
// Work unit: wave-tile = 64 lanes x 4 cells = 256 cells; 3136 tiles total.
// Tile map (b&255) + 256*(4*(b>>8)+wid) spreads active tiles so per-CU
// load is within +6% of ideal regardless of dispatch order.

// ---- per-cell math: pv[0..29], tv[0..24] live in registers, static idx ----
// FP evaluation order matches the previously verified kernel exactly.
__device__ __forceinline__ float cell_math(const float* pv, const float* tv) {
    const float EPS = 1e-6f;
    float cls = 0.0f;
    #pragma unroll
    for (int k = 0; k < CC; ++k) {          // same sequential order as before
        float d = pv[k] - tv[k];
        cls += d * d;
    }
    const float* b1 = pv + 20;  // pred[20..24]
    const float* b2 = pv + 25;  // pred[25..29]
    const float* tb = tv + 20;  // tgt[20..24]

    float obj = (tb[0] == 1.0f) ? 1.0f : 0.0f;

    float t_x1 = tb[0] - tb[2] * 0.5f, t_y1 = tb[1] - tb[3] * 0.5f;
    float t_x2 = tb[0] + tb[2] * 0.5f, t_y2 = tb[1] + tb[3] * 0.5f;
    float t_area = fabsf((t_x2 - t_x1) * (t_y2 - t_y1));

    float a_x1 = b1[0] - b1[2] * 0.5f, a_y1 = b1[1] - b1[3] * 0.5f;
    float a_x2 = b1[0] + b1[2] * 0.5f, a_y2 = b1[1] + b1[3] * 0.5f;
    float iw1 = fmaxf(fminf(a_x2, t_x2) - fmaxf(a_x1, t_x1), 0.0f);
    float ih1 = fmaxf(fminf(a_y2, t_y2) - fmaxf(a_y1, t_y1), 0.0f);
    float inter1 = iw1 * ih1;
    float area1 = fabsf((a_x2 - a_x1) * (a_y2 - a_y1));
    float iou1 = inter1 / (area1 + t_area - inter1 + EPS);

    float c_x1 = b2[0] - b2[2] * 0.5f, c_y1 = b2[1] - b2[3] * 0.5f;
    float c_x2 = b2[0] + b2[2] * 0.5f, c_y2 = b2[1] + b2[3] * 0.5f;
    float iw2 = fmaxf(fminf(c_x2, t_x2) - fmaxf(c_x1, t_x1), 0.0f);
    float ih2 = fmaxf(fminf(c_y2, t_y2) - fmaxf(c_y1, t_y1), 0.0f);
    float inter2 = iw2 * ih2;
    float area2 = fabsf((c_x2 - c_x1) * (c_y2 - c_y1));
    float iou2 = inter2 / (area2 + t_area - inter2 + EPS);

    bool pick1 = iou1 > iou2;
    float r0 = pick1 ? b1[0] : b2[0];
    float r1 = pick1 ? b1[1] : b2[1];
    float r2 = pick1 ? b1[2] : b2[2];
    float r3 = pick1 ? b1[3] : b2[3];
    float r4 = pick1 ? b1[4] : b2[4];

    float dx = r0 - tb[0], dy = r1 - tb[1];
    float xy = dx * dx + dy * dy;
    float dw = sqrtf(r2) - sqrtf(tb[2]);
    float dh = sqrtf(r3) - sqrtf(tb[3]);
    float wh = dw * dw + dh * dh;
    float coord = 5.0f * (xy + wh);
    float dconf = r4 - tb[4];
    float conf = dconf * dconf;

    float noobj = 0.5f * (1.0f - obj) * (b1[4] * b1[4] + b2[4] * b2[4]);
    return obj * (coord + conf + cls) + noobj;
}

// One cell whose 30 pred floats start PO dwords into gp[0..7] (8 float4s)
// and whose 25 tgt floats start TO dwords into gt[0..6] (7 float4s).
// All extraction indices are compile-time -> pure registers, no scratch.
template<int PO, int TO>
__device__ __forceinline__ float cell_from_f4(const float4* __restrict__ gp,
                                              const float4* __restrict__ gt) {
    float pv[32], tv[28];
    #pragma unroll
    for (int k = 0; k < 8; ++k) {
        float4 a = gp[k];
        pv[4 * k] = a.x; pv[4 * k + 1] = a.y; pv[4 * k + 2] = a.z; pv[4 * k + 3] = a.w;
    }
    #pragma unroll
    for (int k = 0; k < 7; ++k) {
        float4 a = gt[k];
        tv[4 * k] = a.x; tv[4 * k + 1] = a.y; tv[4 * k + 2] = a.z; tv[4 * k + 3] = a.w;
    }
    return cell_math(pv + PO, tv + TO);
}

// 4 consecutive cells (one quad): gp = predF4 + q*30, gt = tgtF4 + q*25.
// cell i pred dwords [30i,30i+30), tgt dwords [25i,25i+25).
__device__ __forceinline__ float quad_loss(const float4* __restrict__ gp,
                                           const float4* __restrict__ gt) {
    float s = 0.0f;
    s += cell_from_f4<0, 0>(gp,      gt);       // dwords p0-29  / t0-24
    s += cell_from_f4<2, 1>(gp + 7,  gt + 6);   // p30-59 / t25-49
    s += cell_from_f4<0, 2>(gp + 15, gt + 12);  // p60-89 / t50-74
    s += cell_from_f4<2, 3>(gp + 22, gt + 18);  // p90-119 / t75-99
    return s;
}

__global__ __launch_bounds__(TPB, 3) void yolo_stream(
    const float* __restrict__ pred,
    const float* __restrict__ tgt,
    float* __restrict__ partials,     // [GRID]
    int nCells)
{
    __shared__ float s_red[WAVES];
    const int tid  = threadIdx.x;
    const int lane = tid & 63;
    const int wid  = tid >> 6;
    const int b    = blockIdx.x;

    const int nQuads = nCells >> 2;               // 200704
    const int nTiles = nQuads >> 6;               // 3136 wave-tiles (256 cells)

    // balanced tile map: k in 0..15 per (block-round, wave); tile = (b&255)+256k
    const int k = ((b >> 8) << 2) + wid;
    float loss = 0.0f;

    const float4* predF4 = (const float4*)pred;
    const float4* tgtF4  = (const float4*)tgt;

    for (int tile = (b & 255) + (k << 8); tile < nTiles; tile += NSTREAM) {
        int q = (tile << 6) + lane;               // this lane's quad
        loss += quad_loss(predF4 + (size_t)q * 30, tgtF4 + (size_t)q * 25);
    }

    // generality tail (zero work for N=16384): leftover quads + leftover cells
    if (b == 0 && wid == 0) {
        for (int q = (nTiles << 6) + lane; q < nQuads; q += 64)
            loss += quad_loss(predF4 + (size_t)q * 30, tgtF4 + (size_t)q * 25);
        for (int c = (nQuads << 2) + lane; c < nCells; c += 64) {
            float pv[CELL_PRED], tv[CELL_TGT];
            #pragma unroll
            for (int j = 0; j < CELL_PRED; ++j) pv[j] = pred[(size_t)c * CELL_PRED + j];
            #pragma unroll
            for (int j = 0; j < CELL_TGT; ++j)  tv[j] = tgt[(size_t)c * CELL_TGT + j];
            loss += cell_math(pv, tv);
        }
    }

    // per-wave butterfly, then 4 waves via tiny LDS (single barrier, post-loop)
    #pragma unroll
    for (int off = 32; off > 0; off >>= 1)
        loss += __shfl_down(loss, off, 64);
    if (lane == 0) s_red[wid] = loss;
    __syncthreads();
    if (tid == 0)
        partials[b] = (s_red[0] + s_red[1]) + (s_red[2] + s_red[3]);
}

__global__ __launch_bounds__(REDUCE_BLOCK) void yolo_final_reduce(
    const float* __restrict__ partials, int nPartials, double invN,
    float* __restrict__ out)
{
    __shared__ double s_red[4];
    const float4* p4 = (const float4*)partials;   // d_ws is 16-aligned
    double sum = 0.0;
    for (int i = threadIdx.x; i < (nPartials >> 2); i += REDUCE_BLOCK) {
        float4 v = p4[i];
        sum += (double)v.x + (double)v.y + (double)v.z + (double)v.w;
    }
    for (int i = ((nPartials >> 2) << 2) + threadIdx.x; i < nPartials; i += REDUCE_BLOCK)
        sum += (double)partials[i];
    #pragma unroll
    for (int off = 32; off > 0; off >>= 1)
        sum += __shfl_down(sum, off, 64);
    if ((threadIdx.x & 63) == 0) s_red[threadIdx.x >> 6] = sum;
    __syncthreads();
    if (threadIdx.x == 0) {
        double s = (s_red[0] + s_red[1]) + (s_red[2] + s_red[3]);
        out[0] = (float)(s * invN);
    }
}

extern "C" void kernel_launch(void* const* d_in, const int* in_sizes, int n_in,
                              void* d_out, int out_size, void* d_ws, size_t ws_size,
                              hipStream_t stream) {
    const float* pred = (const float*)d_in[0];
    const float* tgt  = (const float*)d_in[1];
    float* out = (float*)d_out;
    float* partials = (float*)d_ws;

    const int N = in_sizes[0] / (SS * SS * CELL_PRED);   // 16384
    const int nCells = N * SS * SS;                      // 802816

    yolo_stream<<<GRID, TPB, 0, stream>>>(pred, tgt, partials, nCells);
    yolo_final_reduce<<<1, REDUCE_BLOCK, 0, stream>>>(partials, GRID, 1.0 / (double)N, out);
}

// Round 7
// 178.563 us; speedup vs baseline: 1.1552x; 1.1498x over previous
//
#include <hip/hip_runtime.h>
#include <math.h>

// Problem constants (from reference): S=7, NB=2, C=20
#define SS 7
#define CC 20
#define CELL_PRED 30            // C + NB*5  (120 B/cell)
#define CELL_TGT  25            // C + 1 + 4 (100 B/cell)
#define TPB 256                 // 4 waves/block, wave-PRIVATE staging: no hot-loop barriers
#define WAVES 4
#define GRID 512                // 2 blocks/CU resident -> 8 waves/CU; partials fit 4KB ws
#define NW (GRID * WAVES)       // 2048 concurrent wave-streams
#define REDUCE_BLOCK 256

// R11 theory (unchanged from R5; R5 was a compile fail on the builtin's
// operand type): six structures all pin at 66-77us (~2.7 TB/s delivered)
// while per-CU models say <10us -- the wall is chip-level, behind L2. Input
// (176.6MB) FITS the 256MB LLC and the harness re-poisons it every iter, so
// ~half of all reads hit LLC; the HBM miss stream is an LLC-filtered random
// 64B hole pattern -> DRAM row-buffer efficiency collapses to random-read
// rates (1.3-1.8 TB/s) = FETCH/dur every round. m13's 6.3 TB/s copy streams
// PAST the LLC: misses are row-sequential. R6 = R3 structure (contiguous
// 1KB-per-instr global pattern) + nontemporal loads (nt: no LLC allocate) ->
// HBM sees ONE sequential read stream. Decisive: FETCH_SIZE ~86 -> ~176MB.
// __builtin_nontemporal_load requires native vector types, not
// HIP_vector_type structs -> use ext_vector_type and bit-cast.

#define PRED_TILE_B 7680
#define TGT_TILE_B  6400
#define TILE_FLOATS 3520        // (7680+6400)/4 floats per wave-buffer

typedef float vf4 __attribute__((ext_vector_type(4)));
typedef float vf2 __attribute__((ext_vector_type(2)));

__device__ __forceinline__ vf4 ntload4(const float* __restrict__ p) {
    return __builtin_nontemporal_load((const vf4*)p);
}
__device__ __forceinline__ vf2 ntload2(const float* __restrict__ p) {
    return __builtin_nontemporal_load((const vf2*)p);
}
__device__ __forceinline__ float ntload1(const float* __restrict__ p) {
    return __builtin_nontemporal_load(p);
}

__device__ __forceinline__ void stage_tile_nt(const float* __restrict__ pred,
                                              const float* __restrict__ tgt,
                                              size_t t, float* lbuf, int lane)
{
    const float* gp = (const float*)((const char*)pred + t * (size_t)PRED_TILE_B);
    const float* gt = (const float*)((const char*)tgt  + t * (size_t)TGT_TILE_B);

    // ---- issue all 15 coalesced NT loads (contiguous 1KB/512B/256B spans) ----
    vf4 rp[7];
    #pragma unroll
    for (int k = 0; k < 7; ++k) rp[k] = ntload4(gp + (k * 64 + lane) * 4);  // 7x1024B
    vf2 rpt = ntload2(gp + 7168 / 4 + lane * 2);                             // 512B @7168
    vf4 rt[6];
    #pragma unroll
    for (int k = 0; k < 6; ++k) rt[k] = ntload4(gt + (k * 64 + lane) * 4);  // 6x1024B
    float rtt = ntload1(gt + 6144 / 4 + lane);                               // 256B @6144

    // ---- drain into wave-private LDS (compiler inserts counted vmcnt) ----
    vf4* lp4 = (vf4*)lbuf;
    #pragma unroll
    for (int k = 0; k < 7; ++k) lp4[k * 64 + lane] = rp[k];
    ((vf2*)lbuf)[896 + lane] = rpt;
    vf4* lt4 = (vf4*)(lbuf + PRED_TILE_B / 4);
    #pragma unroll
    for (int k = 0; k < 6; ++k) lt4[k * 64 + lane] = rt[k];
    (lbuf + PRED_TILE_B / 4)[1536 + lane] = rtt;
}

// pc = this cell's 30 pred floats (8B-aligned), tc = its 25 tgt floats.
// Works for both LDS (hot path) and global (ragged tail) pointers.
__device__ __forceinline__ float cell_loss_ptr(const float* __restrict__ pc,
                                               const float* __restrict__ tc) {
    const float EPS = 1e-6f;
    float tv[CELL_TGT];
    #pragma unroll
    for (int j = 0; j < CELL_TGT; ++j) tv[j] = tc[j];

    const float2* p2 = (const float2*)pc;
    float cls = 0.0f;
    #pragma unroll
    for (int j = 0; j < 10; ++j) {
        float2 v = p2[j];
        float d0 = v.x - tv[2 * j];
        float d1 = v.y - tv[2 * j + 1];
        cls += d0 * d0;
        cls += d1 * d1;
    }
    float b[10];
    #pragma unroll
    for (int j = 0; j < 5; ++j) {
        float2 v = p2[10 + j];
        b[2 * j] = v.x; b[2 * j + 1] = v.y;
    }
    const float* b1 = b;        // pred[20..24]
    const float* b2 = b + 5;    // pred[25..29]
    const float* tb = tv + CC;  // tgt[20..24]

    float obj = (tb[0] == 1.0f) ? 1.0f : 0.0f;

    float t_x1 = tb[0] - tb[2] * 0.5f, t_y1 = tb[1] - tb[3] * 0.5f;
    float t_x2 = tb[0] + tb[2] * 0.5f, t_y2 = tb[1] + tb[3] * 0.5f;
    float t_area = fabsf((t_x2 - t_x1) * (t_y2 - t_y1));

    float a_x1 = b1[0] - b1[2] * 0.5f, a_y1 = b1[1] - b1[3] * 0.5f;
    float a_x2 = b1[0] + b1[2] * 0.5f, a_y2 = b1[1] + b1[3] * 0.5f;
    float iw1 = fmaxf(fminf(a_x2, t_x2) - fmaxf(a_x1, t_x1), 0.0f);
    float ih1 = fmaxf(fminf(a_y2, t_y2) - fmaxf(a_y1, t_y1), 0.0f);
    float inter1 = iw1 * ih1;
    float area1 = fabsf((a_x2 - a_x1) * (a_y2 - a_y1));
    float iou1 = inter1 / (area1 + t_area - inter1 + EPS);

    float c_x1 = b2[0] - b2[2] * 0.5f, c_y1 = b2[1] - b2[3] * 0.5f;
    float c_x2 = b2[0] + b2[2] * 0.5f, c_y2 = b2[1] + b2[3] * 0.5f;
    float iw2 = fmaxf(fminf(c_x2, t_x2) - fmaxf(c_x1, t_x1), 0.0f);
    float ih2 = fmaxf(fminf(c_y2, t_y2) - fmaxf(c_y1, t_y1), 0.0f);
    float inter2 = iw2 * ih2;
    float area2 = fabsf((c_x2 - c_x1) * (c_y2 - c_y1));
    float iou2 = inter2 / (area2 + t_area - inter2 + EPS);

    bool pick1 = iou1 > iou2;
    float r0 = pick1 ? b1[0] : b2[0];
    float r1 = pick1 ? b1[1] : b2[1];
    float r2 = pick1 ? b1[2] : b2[2];
    float r3 = pick1 ? b1[3] : b2[3];
    float r4 = pick1 ? b1[4] : b2[4];

    float dx = r0 - tb[0], dy = r1 - tb[1];
    float xy = dx * dx + dy * dy;
    float dw = sqrtf(r2) - sqrtf(tb[2]);
    float dh = sqrtf(r3) - sqrtf(tb[3]);
    float wh = dw * dw + dh * dh;
    float coord = 5.0f * (xy + wh);
    float dconf = r4 - tb[4];
    float conf = dconf * dconf;

    float noobj = 0.5f * (1.0f - obj) * (b1[4] * b1[4] + b2[4] * b2[4]);
    return obj * (coord + conf + cls) + noobj;
}

__global__ __launch_bounds__(TPB) void yolo_stream(
    const float* __restrict__ pred,
    const float* __restrict__ tgt,
    float* __restrict__ partials,     // [GRID]
    int nCells)
{
    __shared__ __align__(16) float lds[WAVES][TILE_FLOATS];  // 56,320 B
    __shared__ float s_red[WAVES];
    const int tid  = threadIdx.x;
    const int lane = tid & 63;
    const int wid  = tid >> 6;
    const int gw   = blockIdx.x * WAVES + wid;   // global wave-stream id, 0..NW-1
    const int nTiles = nCells >> 6;              // 12544

    float* buf = lds[wid];                       // wave-private buffer
    float loss = 0.0f;

    // tiles gw, gw+NW, gw+2NW, ...
    const int myT = (gw < nTiles) ? ((nTiles - gw - 1) / NW + 1) : 0;
    size_t t = (size_t)gw;
    for (int i = 0; i < myT; ++i, t += NW) {
        stage_tile_nt(pred, tgt, t, buf, lane);  // 15 NT loads + ds_writes
        loss += cell_loss_ptr(buf + lane * CELL_PRED,
                              buf + (PRED_TILE_B / 4) + lane * CELL_TGT);
    }

    // ragged tail (nCells % 64 != 0; zero for N=16384): direct global path
    if (gw == 0) {
        for (int c = (nTiles << 6) + lane; c < nCells; c += 64)
            loss += cell_loss_ptr(pred + (size_t)c * CELL_PRED,
                                  tgt  + (size_t)c * CELL_TGT);
    }

    // per-wave butterfly, then 4 waves via tiny LDS (single barrier, post-loop)
    #pragma unroll
    for (int off = 32; off > 0; off >>= 1)
        loss += __shfl_down(loss, off, 64);
    if (lane == 0) s_red[wid] = loss;
    __syncthreads();
    if (tid == 0)
        partials[blockIdx.x] = (s_red[0] + s_red[1]) + (s_red[2] + s_red[3]);
}

__global__ __launch_bounds__(REDUCE_BLOCK) void yolo_final_reduce(
    const float* __restrict__ partials, int nPartials, double invN,
    float* __restrict__ out)
{
    __shared__ double s_red[4];
    const float4* p4 = (const float4*)partials;   // d_ws is 16-aligned
    double sum = 0.0;
    for (int i = threadIdx.x; i < (nPartials >> 2); i += REDUCE_BLOCK) {
        float4 v = p4[i];
        sum += (double)v.x + (double)v.y + (double)v.z + (double)v.w;
    }
    for (int i = ((nPartials >> 2) << 2) + threadIdx.x; i < nPartials; i += REDUCE_BLOCK)
        sum += (double)partials[i];
    #pragma unroll
    for (int off = 32; off > 0; off >>= 1)
        sum += __shfl_down(sum, off, 64);
    if ((threadIdx.x & 63) == 0) s_red[threadIdx.x >> 6] = sum;
    __syncthreads();
    if (threadIdx.x == 0) {
        double s = (s_red[0] + s_red[1]) + (s_red[2] + s_red[3]);
        out[0] = (float)(s * invN);
    }
}

extern "C" void kernel_launch(void* const* d_in, const int* in_sizes, int n_in,
                              void* d_out, int out_size, void* d_ws, size_t ws_size,
                              hipStream_t stream) {
    const float* pred = (const float*)d_in[0];
    const float* tgt  = (const float*)d_in[1];
    float* out = (float*)d_out;
    float* partials = (float*)d_ws;

    const int N = in_sizes[0] / (SS * SS * CELL_PRED);   // 16384
    const int nCells = N * SS * SS;                      // 802816

    yolo_stream<<<GRID, TPB, 0, stream>>>(pred, tgt, partials, nCells);
    yolo_final_reduce<<<1, REDUCE_BLOCK, 0, stream>>>(partials, GRID, 1.0 / (double)N, out);
}